// Round 15
// baseline (258.600 us; speedup 1.0000x reference)
//
#include <hip/hip_runtime.h>
#include <math.h>

#define C_IN 72
#define RST 97               // row-buffer stride (floats)
#define NFRAG 21             // 7 n-tiles x 3 k-chunks
#define STG_T (16 * C_IN)    // ushorts per tensor stage tile: [16 pos][72 ch]
#define WAVE_LDS 6912        // per-wave union(stage 6912 B, rowbuf 6208 B)

typedef short short8  __attribute__((ext_vector_type(8)));
typedef float floatx4 __attribute__((ext_vector_type(4)));

// volatile asm load: compiler cannot sink/split/reorder -> true batch.
#define GLD4(dst, ptr) \
    asm volatile("global_load_dwordx4 %0, %1, off" : "=v"(dst) : "v"(ptr))

__device__ __forceinline__ unsigned short f2bf(float f) {   // RNE float->bf16
    unsigned u = __float_as_uint(f);
    u += 0x7FFFu + ((u >> 16) & 1u);
    return (unsigned short)(u >> 16);
}
__device__ __forceinline__ float sigf(float x) {
    return __builtin_amdgcn_rcpf(1.0f + __expf(-x));
}

// ---- kernel 1: pre-pack all B fragments (bf16, MFMA B-operand layout) ----
__global__ void __launch_bounds__(256)
build_bfrags_kernel(const float* __restrict__ w_reg,
                    const float* __restrict__ w_obj,
                    const float* __restrict__ w_cls,
                    short8* __restrict__ frags)
{
    int idx = blockIdx.x * 256 + threadIdx.x;
    if (idx >= NFRAG * 64) return;
    int lane = idx & 63;
    int fi   = idx >> 6;
    int tile = fi / 3, kc = fi - tile * 3;
    int m = lane & 15, quad = lane >> 4;
    const float* wrow;
    bool valid = true;
    if (tile == 0)      { wrow = w_reg + m * C_IN; valid = (m < 12); }
    else if (tile == 1) { wrow = w_obj + m * C_IN; valid = (m < 3); }
    else                { wrow = w_cls + ((tile - 2) * 16 + m) * C_IN; }
    short8 r = {0, 0, 0, 0, 0, 0, 0, 0};
    if (valid && !(kc == 2 && quad != 0)) {
        const float* p = wrow + kc * 32 + quad * 8;
#pragma unroll
        for (int j = 0; j < 8; ++j) r[j] = (short)f2bf(p[j]);
    }
    frags[fi * 64 + lane] = r;
}

// ---- kernel 2: R14/R15 = R11 issue-coverage experiment, minus the hard
// __launch_bounds__(256,4) VGPR cap (prime crash suspect in R13: forced
// 128-VGPR cap on a body with prefetch payload + acc + af + compiler wfrag
// loads live => spill-to-scratch, the only new runtime behavior there).
// Plain (256): if VGPR lands <=128 we still get 4 blocks/CU = 16 waves/CU.
// Theory unchanged: time = lines x latency / (CU x concurrency); ~3.6M 64B
// lines @ ~900cy @ ~30 lines/CU = 80us invariant. Fix = more waves
// concurrently in the load phase. 1000 blocks x 4 indep waves, wave-private
// 6.9KB LDS, volatile-batched loads + 1-slab prefetch, XCD swizzle. ----
__global__ void __launch_bounds__(256)
yolo_head_kernel(const float* __restrict__ fr0, const float* __restrict__ fo0, const float* __restrict__ fc0,
                 const float* __restrict__ fr1, const float* __restrict__ fo1, const float* __restrict__ fc1,
                 const float* __restrict__ b_reg, const float* __restrict__ b_obj,
                 const float* __restrict__ b_cls,
                 const short8* __restrict__ wfrag,
                 float* __restrict__ out)
{
    __shared__ __align__(16) unsigned char smem[4 * WAVE_LDS];   // 27648 B
    const int tid  = threadIdx.x;
    const int wid  = tid >> 6;
    const int lane = tid & 63;
    unsigned short* const stage = (unsigned short*)(smem + wid * WAVE_LDS);
    float*          const row   = (float*)         (smem + wid * WAVE_LDS);

    const int m    = lane & 15;
    const int quad = lane >> 4;
    const int chg  = lane >> 2;    // channel-in-group 0..15
    const int pg   = lane & 3;     // position quarter 0..3

    // bijective XCD swizzle (1000 % 8 == 0): XCD k gets blocks swz in
    // [k*125,(k+1)*125) -> contiguous slabs [k*1000,(k+1)*1000).
    const int swz   = (blockIdx.x & 7) * 125 + (blockIdx.x >> 3);
    const int sbase = (swz * 4 + wid) * 2;     // this wave's 2 consecutive slabs
    const int lvl   = (sbase >= 6400);         // pairs never straddle levels
    const int HW = lvl ? 400 : 1600;
    const int W  = lvl ? 20 : 40;
    const int LO = lvl ? 4800 : 0;
    const float STRIDE = lvl ? 32.0f : 16.0f;
    const float* srcs[3];
    srcs[0] = lvl ? fr1 : fr0;
    srcs[1] = lvl ? fo1 : fo0;
    srcs[2] = lvl ? fc1 : fc0;

    // ---- wave-invariant decode constants ----
    const int a_ = m >> 2, k_ = m & 3;
    float anch;
    {
        float e0, e1;
        if (lvl == 0) { e0 = a_ == 0 ? 12.64f  : a_ == 1 ? 37.88f  : 55.71f;
                        e1 = a_ == 0 ? 19.39f  : a_ == 1 ? 51.48f  : 138.31f; }
        else          { e0 = a_ == 0 ? 126.91f : a_ == 1 ? 131.57f : 279.92f;
                        e1 = a_ == 0 ? 78.23f  : a_ == 1 ? 214.55f : 258.87f; }
        anch = (k_ == 3) ? e1 : e0;
    }
    const float brg = b_reg[m < 12 ? m : 0];
    const float bob = b_obj[m < 3 ? m : 0];
    float bcl[5];
#pragma unroll
    for (int nt = 0; nt < 5; ++nt) bcl[nt] = b_cls[nt * 16 + m];

    // ---- pipelined feature loads: 15 dwordx4 per slab, volatile-forced ----
    floatx4 ld[3][5];
    auto issueT1 = [&](int S) {
        const int Sl = S - (lvl ? 6400 : 0);
        int b, pos0;
        if (!lvl) { b = Sl / 100; pos0 = (Sl - b * 100) * 16; }
        else      { b = Sl / 25;  pos0 = (Sl - b * 25) * 16; }
        const int fb = b * C_IN * HW + pos0 + pg * 4;
#pragma unroll
        for (int t = 0; t < 3; ++t) {
            const float* sp = srcs[t] + fb;
#pragma unroll
            for (int g = 0; g < 4; ++g) {
                const float* p = sp + (g * 16 + chg) * HW;
                GLD4(ld[t][g], p);
            }
        }
        if (lane < 32) {
#pragma unroll
            for (int t = 0; t < 3; ++t) {
                const float* p = srcs[t] + fb + (64 + chg) * HW;
                GLD4(ld[t][4], p);
            }
        }
    };

    issueT1(sbase);

#pragma unroll
    for (int i = 0; i < 2; ++i) {
        const int S  = sbase + i;
        const int Sl = S - (lvl ? 6400 : 0);
        int b, pos0;
        if (!lvl) { b = Sl / 100; pos0 = (Sl - b * 100) * 16; }
        else      { b = Sl / 25;  pos0 = (Sl - b * 25) * 16; }

        // wait this slab's 15 loads. At i=1, the 16 stores of slab 0 (newer,
        // issued after the prefetch loads; "memory"-clobber asm prevents
        // reordering) may remain in flight: vmcnt(16) drains all loads.
        if (i == 0) asm volatile("s_waitcnt vmcnt(0)" ::: "memory");
        else        asm volatile("s_waitcnt vmcnt(16)" ::: "memory");
        __builtin_amdgcn_sched_barrier(0);   // rule 18: cvts are register-only

        // ---- stage: cvt bf16 + transpose-scatter into stage[t][pos][ch] ----
#pragma unroll
        for (int t = 0; t < 3; ++t) {
#pragma unroll
            for (int g = 0; g < 4; ++g)
#pragma unroll
                for (int ii = 0; ii < 4; ++ii)
                    stage[t * STG_T + (pg * 4 + ii) * C_IN + g * 16 + chg] = f2bf(ld[t][g][ii]);
            if (lane < 32)
#pragma unroll
                for (int ii = 0; ii < 4; ++ii)
                    stage[t * STG_T + (pg * 4 + ii) * C_IN + 64 + chg] = f2bf(ld[t][4][ii]);
        }
        asm volatile("s_waitcnt lgkmcnt(0)" ::: "memory");

        // ---- A fragments: direct b128 reads (exact MFMA layout) ----
        short8 af[3][3];
#pragma unroll
        for (int t = 0; t < 3; ++t) {
            const unsigned short* tp = stage + t * STG_T + m * C_IN;
            af[t][0] = *(const short8*)(tp + quad * 8);
            af[t][1] = *(const short8*)(tp + 32 + quad * 8);
            short8 v = *(const short8*)(tp + 64);
            if (quad) v = (short8){0, 0, 0, 0, 0, 0, 0, 0};
            af[t][2] = v;
        }
        asm volatile("s_waitcnt lgkmcnt(0)" ::: "memory");  // frags landed; region reusable

        // ---- prefetch: slab 1's loads fly under slab 0's MFMA/decode/write ----
        if (i == 0) issueT1(S + 1);

        // ---- MFMA: 21 tiles, B from L2-resident wfrag (compiler-scheduled,
        // always-hot 21.5KB; vmcnt arithmetic above is robust to interleave) ----
        floatx4 accR = {0, 0, 0, 0}, accO = {0, 0, 0, 0}, accC[5];
#pragma unroll
        for (int kc = 0; kc < 3; ++kc)
            accR = __builtin_amdgcn_mfma_f32_16x16x32_bf16(af[0][kc], wfrag[(0 * 3 + kc) * 64 + lane], accR, 0, 0, 0);
#pragma unroll
        for (int kc = 0; kc < 3; ++kc)
            accO = __builtin_amdgcn_mfma_f32_16x16x32_bf16(af[1][kc], wfrag[(1 * 3 + kc) * 64 + lane], accO, 0, 0, 0);
#pragma unroll
        for (int nt = 0; nt < 5; ++nt) {
            floatx4 a4 = {0, 0, 0, 0};
#pragma unroll
            for (int kc = 0; kc < 3; ++kc)
                a4 = __builtin_amdgcn_mfma_f32_16x16x32_bf16(af[2][kc], wfrag[((nt + 2) * 3 + kc) * 64 + lane], a4, 0, 0, 0);
            accC[nt] = a4;
        }

        // ---- decode into rowbuf (unions with stage; frags already consumed) ----
#pragma unroll
        for (int ii = 0; ii < 4; ++ii) {
            const int prel = quad * 4 + ii;
            const int pg_  = pos0 + prel;
            const int gyi  = lvl ? (pg_ / 20) : (pg_ / 40);
            const float gx = (float)(pg_ - gyi * W);
            const float gy = (float)gyi;

            if (m < 12) {
                float sg = sigf(accR[ii] + brg);
                float v;
                if (k_ == 0)      v = (sg * 2.0f - 0.5f + gx) * STRIDE;
                else if (k_ == 1) v = (sg * 2.0f - 0.5f + gy) * STRIDE;
                else { float t2 = sg * 2.0f; v = t2 * t2 * anch; }
                row[prel * RST + a_ * 5 + k_] = v;
            }
            if (m < 3)
                row[prel * RST + m * 5 + 4] = sigf(accO[ii] + bob);

            float e[5];
            float s = 0.f;
#pragma unroll
            for (int nt = 0; nt < 5; ++nt) {
                e[nt] = __expf(accC[nt][ii] + bcl[nt]);
                s += e[nt];
            }
            s += __shfl_xor(s, 1, 16);
            s += __shfl_xor(s, 2, 16);
            s += __shfl_xor(s, 4, 16);
            s += __shfl_xor(s, 8, 16);
            const float inv = __builtin_amdgcn_rcpf(s);
#pragma unroll
            for (int nt = 0; nt < 5; ++nt)
                row[prel * RST + 15 + nt * 16 + m] = e[nt] * inv;
        }
        asm volatile("s_waitcnt lgkmcnt(0)" ::: "memory");  // rowbuf visible to writer

        // ---- writer: 16 dwordx4 stores/slab (magic-div by 255, F<4096) ----
        float* outp = out + ((size_t)b * 510000 + LO * 85 + pos0 * 255);
#pragma unroll
        for (int s = 0; s < 16; ++s) {
            if (!(s == 15 && lane >= 60)) {          // F 4080..4095 don't exist
                floatx4 v;
#pragma unroll
                for (int j = 0; j < 4; ++j) {
                    const int F  = s * 256 + lane * 4 + j;
                    const int p  = (F * 4113) >> 20;      // floor(F/255), F<4096
                    const int k  = F - p * 255;
                    const int a  = (k >= 85) + (k >= 170);
                    const int kk = k - a * 85;
                    const int wi = (kk < 5) ? (a * 5 + kk) : (15 + (kk - 5));
                    v[j] = row[p * RST + wi];
                }
                *(floatx4*)(outp + s * 256 + lane * 4) = v;
            }
        }
    }
}

extern "C" void kernel_launch(void* const* d_in, const int* in_sizes, int n_in,
                              void* d_out, int out_size, void* d_ws, size_t ws_size,
                              hipStream_t stream) {
    (void)in_sizes; (void)n_in; (void)ws_size; (void)out_size;
    const float* fr0  = (const float*)d_in[0];
    const float* fo0  = (const float*)d_in[1];
    const float* fc0  = (const float*)d_in[2];
    const float* fr1  = (const float*)d_in[3];
    const float* fo1  = (const float*)d_in[4];
    const float* fc1  = (const float*)d_in[5];
    const float* wreg = (const float*)d_in[6];
    const float* breg = (const float*)d_in[7];
    const float* wobj = (const float*)d_in[8];
    const float* bobj = (const float*)d_in[9];
    const float* wcls = (const float*)d_in[10];
    const float* bcls = (const float*)d_in[11];
    float* out = (float*)d_out;
    short8* frags = (short8*)d_ws;    // 21*64*16 = 21504 B

    // d_ws is re-poisoned before every call -> rebuild fragments every call
    build_bfrags_kernel<<<6, 256, 0, stream>>>(wreg, wobj, wcls, frags);

    // 1000 blocks x 4 waves x 2 slabs = 8000 slabs; 16 waves/CU target
    yolo_head_kernel<<<1000, 256, 0, stream>>>(
        fr0, fo0, fc0, fr1, fo1, fc1,
        breg, bobj, bcls, frags, out);
}

// Round 17
// 246.536 us; speedup vs baseline: 1.0489x; 1.0489x over previous
//
#include <hip/hip_runtime.h>
#include <math.h>

#define C_IN 72
#define RST 97         // row-buffer stride (floats): 0..14 box, 15..94 cls(prescaled)
#define NFRAG 21       // 7 n-tiles x 3 k-chunks
#define STG_T (16 * C_IN)     // ushorts per tensor stage tile: [16 pos][72 ch]
#define SMEM_BYTES 6912       // max(3*16*72*2 = 6912, 16*97*4 = 6208)

typedef short short8  __attribute__((ext_vector_type(8)));
typedef float floatx4 __attribute__((ext_vector_type(4)));

__device__ __forceinline__ unsigned short f2bf(float f) {   // RNE float->bf16
    unsigned u = __float_as_uint(f);
    u += 0x7FFFu + ((u >> 16) & 1u);
    return (unsigned short)(u >> 16);
}
__device__ __forceinline__ float sigf(float x) {
    return __builtin_amdgcn_rcpf(1.0f + __expf(-x));
}

// ---- kernel 1: pre-pack all B fragments (bf16, MFMA B-operand layout) ----
// frag fi = tile*3+kc; lane holds B[n=lane&15][k=quad*8+j].
// Tiles: 0=reg(12 valid), 1=obj(3 valid), 2..6=cls rows nt*16+m. k>=72 zero-pad.
__global__ void __launch_bounds__(256)
build_bfrags_kernel(const float* __restrict__ w_reg,
                    const float* __restrict__ w_obj,
                    const float* __restrict__ w_cls,
                    short8* __restrict__ frags)
{
    int idx = blockIdx.x * 256 + threadIdx.x;
    if (idx >= NFRAG * 64) return;
    int lane = idx & 63;
    int fi   = idx >> 6;
    int tile = fi / 3, kc = fi - tile * 3;
    int m = lane & 15, quad = lane >> 4;
    const float* wrow;
    bool valid = true;
    if (tile == 0)      { wrow = w_reg + m * C_IN; valid = (m < 12); }
    else if (tile == 1) { wrow = w_obj + m * C_IN; valid = (m < 3); }
    else                { wrow = w_cls + ((tile - 2) * 16 + m) * C_IN; }
    short8 r = {0, 0, 0, 0, 0, 0, 0, 0};
    if (valid && !(kc == 2 && quad != 0)) {
        const float* p = wrow + kc * 32 + quad * 8;
#pragma unroll
        for (int j = 0; j < 8; ++j) r[j] = (short)f2bf(p[j]);
    }
    frags[fi * 64 + lane] = r;
}

// ---- kernel 2: main head. ONE WAVE per block (best-measured config: 16
// wg/CU slot residency, occ 43%, 76.7us). Session conclusion after 7
// structural variants (occ 17-48%, FETCH 57-108MB, batched/unbatched,
// staged/unstaged, pipelined/serial): duration pinned 77-91us; this access
// mix (16-line scatter reads + 4-line scatter stores) equilibrates at
// ~3 TB/s effective and the simplest structure is the fastest. ----
__global__ void __launch_bounds__(64, 4)
yolo_head_kernel(const float* __restrict__ fr0, const float* __restrict__ fo0, const float* __restrict__ fc0,
                 const float* __restrict__ fr1, const float* __restrict__ fo1, const float* __restrict__ fc1,
                 const float* __restrict__ b_reg, const float* __restrict__ b_obj,
                 const float* __restrict__ b_cls,
                 const short8* __restrict__ wfrag,
                 float* __restrict__ out)
{
    // stage (bf16 [3][16][72], 6912 B) and rowbuf (f32 [16][97], 6208 B) are
    // time-disjoint -> union in one LDS block to keep 16 wg/CU resident.
    __shared__ __align__(16) unsigned char smem[SMEM_BYTES];
    unsigned short* const stage = (unsigned short*)smem;
    float* const row = (float*)smem;

    const int bid  = blockIdx.x;
    const int lane = threadIdx.x;
    const int m    = lane & 15;
    const int quad = lane >> 4;
    const int chg  = lane >> 2;   // channel-in-group 0..15
    const int pg   = lane & 3;    // position quarter 0..3

    // level mapping: 6400 L0 blocks (100/image) then 1600 L1 blocks (25/image);
    // 16-pos slabs never cross image/level boundaries.
    int lvl, b, pos0, HW, W, LO;
    const float *fr, *fo, *fc;
    if (bid < 6400) {
        lvl = 0; b = bid / 100; pos0 = (bid - b * 100) * 16;
        HW = 1600; W = 40; LO = 0; fr = fr0; fo = fo0; fc = fc0;
    } else {
        int t = bid - 6400;
        lvl = 1; b = t / 25; pos0 = (t - b * 25) * 16;
        HW = 400; W = 20; LO = 4800; fr = fr1; fo = fo1; fc = fc1;
    }
    const float STRIDE = lvl ? 32.0f : 16.0f;

    // ---- phase A: dense global loads. lane (chg,pg) owns channel chg of
    // group g at positions pg*4..pg*4+3 -> dwordx4. 4 full + 1 half per
    // tensor = 15 wave-instructions. ----
    const int fbase = b * C_IN * HW + pos0 + pg * 4;
    const float* srcs[3] = {fr, fo, fc};
    floatx4 ld[3][5];
#pragma unroll
    for (int t = 0; t < 3; ++t) {
        const float* sp = srcs[t] + fbase;
#pragma unroll
        for (int g = 0; g < 4; ++g)
            ld[t][g] = *(const floatx4*)(sp + (g * 16 + chg) * HW);
        if (lane < 32)          // channels 64..71 (chg 0..7)
            ld[t][4] = *(const floatx4*)(sp + (64 + chg) * HW);
    }

    // ---- phase B: cvt to bf16 + transpose-scatter into stage[t][pos][ch] ----
#pragma unroll
    for (int t = 0; t < 3; ++t) {
#pragma unroll
        for (int g = 0; g < 4; ++g)
#pragma unroll
            for (int i = 0; i < 4; ++i)
                stage[t * STG_T + (pg * 4 + i) * C_IN + g * 16 + chg] = f2bf(ld[t][g][i]);
        if (lane < 32)
#pragma unroll
            for (int i = 0; i < 4; ++i)
                stage[t * STG_T + (pg * 4 + i) * C_IN + 64 + chg] = f2bf(ld[t][4][i]);
    }
    // wave-local: DS pipe is in-order, fence stops compiler reordering only
    __asm__ volatile("s_waitcnt lgkmcnt(0)" ::: "memory");

    // ---- phase C: A fragments as direct b128 reads (exact MFMA layout) ----
    short8 af[3][3];
#pragma unroll
    for (int t = 0; t < 3; ++t) {
        const unsigned short* tp = stage + t * STG_T + m * C_IN;
        af[t][0] = *(const short8*)(tp + quad * 8);
        af[t][1] = *(const short8*)(tp + 32 + quad * 8);
        short8 v = *(const short8*)(tp + 64);        // ch 64..71
        if (quad) v = (short8){0, 0, 0, 0, 0, 0, 0, 0};
        af[t][2] = v;
    }
    // frag data must land before rowbuf writes overwrite the stage region
    __asm__ volatile("s_waitcnt lgkmcnt(0)" ::: "memory");

    // ---- MFMA: 21 tiles, B streamed from L2-resident prepacked frags ----
    floatx4 accR = {0, 0, 0, 0}, accO = {0, 0, 0, 0}, accC[5];
#pragma unroll
    for (int kc = 0; kc < 3; ++kc)
        accR = __builtin_amdgcn_mfma_f32_16x16x32_bf16(af[0][kc], wfrag[(0 * 3 + kc) * 64 + lane], accR, 0, 0, 0);
#pragma unroll
    for (int kc = 0; kc < 3; ++kc)
        accO = __builtin_amdgcn_mfma_f32_16x16x32_bf16(af[1][kc], wfrag[(1 * 3 + kc) * 64 + lane], accO, 0, 0, 0);
#pragma unroll
    for (int nt = 0; nt < 5; ++nt) {
        floatx4 a4 = {0, 0, 0, 0};
#pragma unroll
        for (int kc = 0; kc < 3; ++kc)
            a4 = __builtin_amdgcn_mfma_f32_16x16x32_bf16(af[2][kc], wfrag[((nt + 2) * 3 + kc) * 64 + lane], a4, 0, 0, 0);
        accC[nt] = a4;
    }

    // ---- decode, all register-parallel. D layout: col(=channel)=lane&15,
    // row(=position)=quad*4+i ----
    const int a_ = m >> 2, k_ = m & 3;          // box channel split (m<12)
    float anch;
    {   // anchor for (lvl, a_, k_ parity): w-anchor for k_==2, h-anchor for k_==3
        float e0, e1;
        if (lvl == 0) { e0 = a_ == 0 ? 12.64f  : a_ == 1 ? 37.88f  : 55.71f;
                        e1 = a_ == 0 ? 19.39f  : a_ == 1 ? 51.48f  : 138.31f; }
        else          { e0 = a_ == 0 ? 126.91f : a_ == 1 ? 131.57f : 279.92f;
                        e1 = a_ == 0 ? 78.23f  : a_ == 1 ? 214.55f : 258.87f; }
        anch = (k_ == 3) ? e1 : e0;
    }
    const float brg = b_reg[m < 12 ? m : 0];
    const float bob = b_obj[m < 3 ? m : 0];
    float bcl[5];
#pragma unroll
    for (int nt = 0; nt < 5; ++nt) bcl[nt] = b_cls[nt * 16 + m];

#pragma unroll
    for (int i = 0; i < 4; ++i) {
        const int prel = quad * 4 + i;
        const int pg_  = pos0 + prel;
        const int gyi  = lvl ? (pg_ / 20) : (pg_ / 40);     // const-div magic
        const float gx = (float)(pg_ - gyi * W);
        const float gy = (float)gyi;

        if (m < 12) {           // box fields: each lane owns one (a,k) channel
            float sg = sigf(accR[i] + brg);
            float v;
            if (k_ == 0)      v = (sg * 2.0f - 0.5f + gx) * STRIDE;
            else if (k_ == 1) v = (sg * 2.0f - 0.5f + gy) * STRIDE;
            else { float t2 = sg * 2.0f; v = t2 * t2 * anch; }
            row[prel * RST + a_ * 5 + k_] = v;
        }
        if (m < 3)              // objectness
            row[prel * RST + m * 5 + 4] = sigf(accO[i] + bob);

        // cls: exp + 16-lane butterfly for the denom, scale BEFORE scatter
        float e[5];
        float s = 0.f;
#pragma unroll
        for (int nt = 0; nt < 5; ++nt) {
            // softmax shift-invariant; logits O(1), exp cannot overflow fp32
            e[nt] = __expf(accC[nt][i] + bcl[nt]);
            s += e[nt];
        }
        s += __shfl_xor(s, 1, 16);
        s += __shfl_xor(s, 2, 16);
        s += __shfl_xor(s, 4, 16);
        s += __shfl_xor(s, 8, 16);
        const float inv = __builtin_amdgcn_rcpf(s);
#pragma unroll
        for (int nt = 0; nt < 5; ++nt)
            row[prel * RST + 15 + nt * 16 + m] = e[nt] * inv;
    }
    // single wave: drain DS so writer reads see the decode's ds_writes
    __asm__ volatile("s_waitcnt lgkmcnt(0)" ::: "memory");

    // ---- writer: per-lane slot descriptors, plain copies, coalesced stores ----
    int wi0[4];
#pragma unroll
    for (int j = 0; j < 4; ++j) {
        int f = lane + 64 * j;
        int k = (f > 254) ? 0 : f;
        int a  = (k >= 85) + (k >= 170);
        int kk = k - a * 85;
        wi0[j] = (kk < 5) ? (a * 5 + kk) : (15 + (kk - 5));
    }
    float* outp = out + ((size_t)b * 510000 + LO * 85 + pos0 * 255);
    for (int p = 0; p < 16; ++p) {
        const float* rr = row + p * RST;
        float* po = outp + p * 255 + lane;
#pragma unroll
        for (int j = 0; j < 4; ++j) {
            if (!(lane == 63 && j == 3))            // f=255 masked
                po[64 * j] = rr[wi0[j]];
        }
    }
}

extern "C" void kernel_launch(void* const* d_in, const int* in_sizes, int n_in,
                              void* d_out, int out_size, void* d_ws, size_t ws_size,
                              hipStream_t stream) {
    (void)in_sizes; (void)n_in; (void)ws_size; (void)out_size;
    const float* fr0  = (const float*)d_in[0];
    const float* fo0  = (const float*)d_in[1];
    const float* fc0  = (const float*)d_in[2];
    const float* fr1  = (const float*)d_in[3];
    const float* fo1  = (const float*)d_in[4];
    const float* fc1  = (const float*)d_in[5];
    const float* wreg = (const float*)d_in[6];
    const float* breg = (const float*)d_in[7];
    const float* wobj = (const float*)d_in[8];
    const float* bobj = (const float*)d_in[9];
    const float* wcls = (const float*)d_in[10];
    const float* bcls = (const float*)d_in[11];
    float* out = (float*)d_out;
    short8* frags = (short8*)d_ws;    // 21*64*16 = 21504 B

    // d_ws is re-poisoned before every call -> rebuild fragments every call
    build_bfrags_kernel<<<6, 256, 0, stream>>>(wreg, wobj, wcls, frags);

    // 6400 level-0 + 1600 level-1 single-wave blocks
    yolo_head_kernel<<<8000, 64, 0, stream>>>(
        fr0, fo0, fc0, fr1, fo1, fc1,
        breg, bobj, bcls, frags, out);
}